// Round 1
// baseline (158.613 us; speedup 1.0000x reference)
//
#include <hip/hip_runtime.h>

#define BLOCK 256
#define ITEMS 4
#define CHUNK (BLOCK * ITEMS)
#define VMAX 2.2f

struct DSum { double x, y; };

// Kernel 1: per-block partial sums of tanh(U)*vmax*dt, fp64 block reduce.
__global__ __launch_bounds__(BLOCK) void wi_partial(
    const float* __restrict__ U, const float* __restrict__ dtp,
    DSum* __restrict__ bsum, int N)
{
  const int t = threadIdx.x;
  const long base = (long)blockIdx.x * CHUNK + (long)t * ITEMS;
  const float dt = *dtp;
  float sx = 0.f, sy = 0.f;
  if (base + ITEMS <= N) {
    const float4* p = (const float4*)(U + 2 * base);
    float4 a = p[0], b = p[1];
    sx = tanhf(a.x) + tanhf(a.z) + tanhf(b.x) + tanhf(b.z);
    sy = tanhf(a.y) + tanhf(a.w) + tanhf(b.y) + tanhf(b.w);
  } else {
    for (int i = 0; i < ITEMS; ++i) {
      long idx = base + i;
      if (idx < N) { sx += tanhf(U[2*idx]); sy += tanhf(U[2*idx+1]); }
    }
  }
  const float sc = VMAX * dt;
  __shared__ double lx[BLOCK], ly[BLOCK];
  lx[t] = (double)(sx * sc);
  ly[t] = (double)(sy * sc);
  __syncthreads();
  for (int off = BLOCK / 2; off > 0; off >>= 1) {
    if (t < off) { lx[t] += lx[t + off]; ly[t] += ly[t + off]; }
    __syncthreads();
  }
  if (t == 0) { bsum[blockIdx.x].x = lx[0]; bsum[blockIdx.x].y = ly[0]; }
}

// Kernel 2: single-block fp64 exclusive scan of block sums (in place).
__global__ __launch_bounds__(BLOCK) void wi_scan_blocks(DSum* bsum, int nblocks)
{
  const int t = threadIdx.x;
  const int per = (nblocks + BLOCK - 1) / BLOCK;
  const int s = t * per;
  const int e = min(s + per, nblocks);
  double tx = 0.0, ty = 0.0;
  for (int i = s; i < e; ++i) { tx += bsum[i].x; ty += bsum[i].y; }
  __shared__ double lx[BLOCK], ly[BLOCK];
  lx[t] = tx; ly[t] = ty;
  __syncthreads();
  for (int off = 1; off < BLOCK; off <<= 1) {
    double ax = lx[t], ay = ly[t];
    double bx = 0.0, by = 0.0;
    if (t >= off) { bx = lx[t - off]; by = ly[t - off]; }
    __syncthreads();
    lx[t] = ax + bx; ly[t] = ay + by;
    __syncthreads();
  }
  double rx = (t > 0) ? lx[t - 1] : 0.0;
  double ry = (t > 0) ? ly[t - 1] : 0.0;
  for (int i = s; i < e; ++i) {
    double vx = bsum[i].x, vy = bsum[i].y;
    bsum[i].x = rx; bsum[i].y = ry;
    rx += vx; ry += vy;
  }
}

// Kernel 3: recompute uv, add block offset + local scan, emit [pos, theta, v].
__global__ __launch_bounds__(BLOCK) void wi_emit(
    const float* __restrict__ U, const float* __restrict__ x0,
    const float* __restrict__ dtp, const DSum* __restrict__ boff,
    float* __restrict__ out, int N)
{
  const int t = threadIdx.x;
  const long base = (long)blockIdx.x * CHUNK + (long)t * ITEMS;
  const float dt = *dtp;
  float vx[ITEMS], vy[ITEMS];
  const bool full = (base + ITEMS <= N);
  if (full) {
    const float4* p = (const float4*)(U + 2 * base);
    float4 a = p[0], b = p[1];
    vx[0] = tanhf(a.x) * VMAX; vy[0] = tanhf(a.y) * VMAX;
    vx[1] = tanhf(a.z) * VMAX; vy[1] = tanhf(a.w) * VMAX;
    vx[2] = tanhf(b.x) * VMAX; vy[2] = tanhf(b.y) * VMAX;
    vx[3] = tanhf(b.z) * VMAX; vy[3] = tanhf(b.w) * VMAX;
  } else {
    for (int i = 0; i < ITEMS; ++i) {
      long idx = base + i;
      if (idx < N) { vx[i] = tanhf(U[2*idx]) * VMAX; vy[i] = tanhf(U[2*idx+1]) * VMAX; }
      else { vx[i] = 0.f; vy[i] = 0.f; }
    }
  }
  // thread-local inclusive prefix of uv*dt
  float px[ITEMS], py[ITEMS];
  float sx = 0.f, sy = 0.f;
  for (int i = 0; i < ITEMS; ++i) {
    sx += vx[i] * dt; px[i] = sx;
    sy += vy[i] * dt; py[i] = sy;
  }
  // block-wide inclusive scan (Hillis-Steele) of thread totals, fp32
  __shared__ float lsx[BLOCK], lsy[BLOCK];
  lsx[t] = sx; lsy[t] = sy;
  __syncthreads();
  for (int off = 1; off < BLOCK; off <<= 1) {
    float ax = lsx[t], ay = lsy[t];
    float bx = 0.f, by = 0.f;
    if (t >= off) { bx = lsx[t - off]; by = lsy[t - off]; }
    __syncthreads();
    lsx[t] = ax + bx; lsy[t] = ay + by;
    __syncthreads();
  }
  const float ex = (t > 0) ? lsx[t - 1] : 0.f;
  const float ey = (t > 0) ? lsy[t - 1] : 0.f;
  const double ox = boff[blockIdx.x].x + (double)x0[0];
  const double oy = boff[blockIdx.x].y + (double)x0[1];
  for (int i = 0; i < ITEMS; ++i) {
    long idx = base + i;
    if (idx < N) {
      float posx = (float)(ox + (double)(ex + px[i]));
      float posy = (float)(oy + (double)(ey + py[i]));
      float theta = atan2f(vy[i], vx[i] + 1e-9f);
      float vv = sqrtf(vx[i] * vx[i] + vy[i] * vy[i] + 1e-12f);
      vv = fminf(vv, VMAX);
      ((float4*)out)[1 + idx] = make_float4(posx, posy, theta, vv);
    }
  }
  if (blockIdx.x == 0 && t == 0) {
    out[0] = x0[0]; out[1] = x0[1]; out[2] = x0[2]; out[3] = x0[3];
  }
}

extern "C" void kernel_launch(void* const* d_in, const int* in_sizes, int n_in,
                              void* d_out, int out_size, void* d_ws, size_t ws_size,
                              hipStream_t stream) {
  const float* x0 = (const float*)d_in[0];
  const float* U  = (const float*)d_in[1];
  const float* dt = (const float*)d_in[2];
  float* out = (float*)d_out;
  const int N = in_sizes[1] / 2;
  const int nblocks = (N + CHUNK - 1) / CHUNK;
  DSum* bsum = (DSum*)d_ws;  // nblocks * 16 bytes (16384 * 16 = 256 KiB)

  wi_partial<<<nblocks, BLOCK, 0, stream>>>(U, dt, bsum, N);
  wi_scan_blocks<<<1, BLOCK, 0, stream>>>(bsum, nblocks);
  wi_emit<<<nblocks, BLOCK, 0, stream>>>(U, x0, dt, bsum, out, N);
}